// Round 1
// baseline (3332.476 us; speedup 1.0000x reference)
//
#include <hip/hip_runtime.h>
#include <hip/hip_bf16.h>
#include <cstddef>
#include <cstdint>

// Problem constants
constexpr int V  = 32000;
constexpr int D  = 256;
constexpr int T  = 1024;
constexpr int B  = 8;
constexpr int L  = 4;
constexpr int H  = 4;
constexpr int HS = 64;     // D/H
constexpr int FF = 1024;   // 4*D
constexpr int CH = 256;
constexpr int NOUT = 2;
constexpr int M_TOK = B * T;   // 8192 rows in the token stream

// ---------------------------------------------------------------------------
// Embedding: x[b,t,:] = tok_emb[idx[b,t],:] + pos_emb[t,:]
// One wave per token, float4 per lane (64 lanes * 16B = 1024B = full row).
// ---------------------------------------------------------------------------
__global__ __launch_bounds__(256) void k_embed(const int* __restrict__ idx,
                                               const float* __restrict__ tok,
                                               const float* __restrict__ pos,
                                               float* __restrict__ x) {
  int wid  = threadIdx.x >> 6;
  int lane = threadIdx.x & 63;
  int row  = blockIdx.x * 4 + wid;          // token index 0..8191
  int t    = row & (T - 1);
  int v    = idx[row];
  const float4* t4 = (const float4*)(tok + (size_t)v * D);
  const float4* p4 = (const float4*)(pos + (size_t)t * D);
  float4 a = t4[lane];
  float4 b = p4[lane];
  float4 r;
  r.x = a.x + b.x; r.y = a.y + b.y; r.z = a.z + b.z; r.w = a.w + b.w;
  ((float4*)(x + (size_t)row * D))[lane] = r;
}

// ---------------------------------------------------------------------------
// LayerNorm over D=256. One wave per row; lane holds 4 consecutive elements.
// ---------------------------------------------------------------------------
__global__ __launch_bounds__(256) void k_ln(const float* __restrict__ xin,
                                            const float* __restrict__ g,
                                            const float* __restrict__ bt,
                                            float* __restrict__ xout) {
  int wid  = threadIdx.x >> 6;
  int lane = threadIdx.x & 63;
  int row  = blockIdx.x * 4 + wid;
  float4 v = ((const float4*)(xin + (size_t)row * D))[lane];
  float s = v.x + v.y + v.z + v.w;
#pragma unroll
  for (int mk = 32; mk; mk >>= 1) s += __shfl_xor(s, mk);
  float mean = s * (1.0f / D);
  float4 dv;
  dv.x = v.x - mean; dv.y = v.y - mean; dv.z = v.z - mean; dv.w = v.w - mean;
  float q = dv.x * dv.x + dv.y * dv.y + dv.z * dv.z + dv.w * dv.w;
#pragma unroll
  for (int mk = 32; mk; mk >>= 1) q += __shfl_xor(q, mk);
  float rs = rsqrtf(q * (1.0f / D) + 1e-5f);
  float4 g4 = ((const float4*)g)[lane];
  float4 b4 = ((const float4*)bt)[lane];
  float4 o;
  o.x = dv.x * rs * g4.x + b4.x;
  o.y = dv.y * rs * g4.y + b4.y;
  o.z = dv.z * rs * g4.z + b4.z;
  o.w = dv.w * rs * g4.w + b4.w;
  ((float4*)(xout + (size_t)row * D))[lane] = o;
}

// ---------------------------------------------------------------------------
// Re-layout per-head QKV weights [L,H,D,HS] -> row-major [L,3,K=256,N=256]
// with column n = h*64+e, so GEMMs become standard.
// ---------------------------------------------------------------------------
__global__ __launch_bounds__(256) void k_prep_qkv(const float* __restrict__ Wq,
                                                  const float* __restrict__ Wk,
                                                  const float* __restrict__ Wv,
                                                  float* __restrict__ wrm) {
  int bi = blockIdx.x;           // 0..(L*3*256-1)
  int n  = threadIdx.x;          // 0..255
  int l  = bi / 768;
  int rem = bi - l * 768;
  int z  = rem >> 8;             // 0..2
  int k  = rem & 255;
  const float* src = (z == 0) ? Wq : ((z == 1) ? Wk : Wv);
  float val = src[(( (size_t)l * H + (n >> 6)) * D + k) * HS + (n & 63)];
  wrm[(((size_t)(l * 3 + z) * D) + k) * D + n] = val;
}

// ---------------------------------------------------------------------------
// Generic fp32 tiled GEMM: C[M,N] (+=) A[M,K] * B[K,N] (+ bias) (relu)
// 64x64 tile per 256-thread block, 4x4 per thread, K-step 16.
// Grid: (M/64, N/64).
// ---------------------------------------------------------------------------
template <int BIAS, int RELU, int RESID>
__global__ __launch_bounds__(256) void k_gemm(const float* __restrict__ A, int lda,
                                              const float* __restrict__ Bm, int ldb,
                                              const float* __restrict__ bias,
                                              float* __restrict__ C, int ldc,
                                              int K) {
  __shared__ float As[64][17];
  __shared__ float Bs[16][65];
  int tid = threadIdx.x;
  int tx = tid & 15, ty = tid >> 4;
  int row0 = blockIdx.x * 64;
  int col0 = blockIdx.y * 64;
  float acc[4][4] = {};
  for (int k0 = 0; k0 < K; k0 += 16) {
#pragma unroll
    for (int i = 0; i < 4; i++) {
      int e = tid + i * 256;
      int r = e >> 4, c = e & 15;
      As[r][c] = A[(size_t)(row0 + r) * lda + k0 + c];
    }
#pragma unroll
    for (int i = 0; i < 4; i++) {
      int e = tid + i * 256;
      int r = e >> 6, c = e & 63;
      Bs[r][c] = Bm[(size_t)(k0 + r) * ldb + col0 + c];
    }
    __syncthreads();
#pragma unroll
    for (int kk = 0; kk < 16; kk++) {
      float a[4], bb[4];
#pragma unroll
      for (int i = 0; i < 4; i++) a[i] = As[ty * 4 + i][kk];
#pragma unroll
      for (int j = 0; j < 4; j++) bb[j] = Bs[kk][tx * 4 + j];
#pragma unroll
      for (int i = 0; i < 4; i++)
#pragma unroll
        for (int j = 0; j < 4; j++) acc[i][j] += a[i] * bb[j];
    }
    __syncthreads();
  }
#pragma unroll
  for (int i = 0; i < 4; i++) {
#pragma unroll
    for (int j = 0; j < 4; j++) {
      int r = row0 + ty * 4 + i;
      int c = col0 + tx * 4 + j;
      float vv = acc[i][j];
      if (BIAS) vv += bias[c];
      if (RELU) vv = fmaxf(vv, 0.0f);
      float* p = &C[(size_t)r * ldc + c];
      if (RESID) vv += *p;
      *p = vv;
    }
  }
}

// ---------------------------------------------------------------------------
// QK^T + softmax, writes normalized attention rows directly to d_out maps.
// Block: (t-tile of 8 rows, h, b). Scores tile staged fully in LDS.
// q,k stored as [B*T][D] with column h*64+e.
// ---------------------------------------------------------------------------
__global__ __launch_bounds__(256) void k_attn_qk(const float* __restrict__ qb,
                                                 const float* __restrict__ kb,
                                                 float* __restrict__ wout,
                                                 int l) {
  __shared__ float sc[8][T];      // 32 KB
  __shared__ float qs[8][65];
  __shared__ float ks[64][65];    // padded: conflict-free dot reads
  int b  = blockIdx.z;
  int h  = blockIdx.y;
  int t0 = blockIdx.x * 8;
  int tid = threadIdx.x;
  // load 8 q rows (head slice)
#pragma unroll
  for (int i = 0; i < 2; i++) {
    int e = tid + i * 256;
    int r = e >> 6, c = e & 63;
    qs[r][c] = qb[(size_t)(b * T + t0 + r) * D + h * HS + c];
  }
  for (int s0 = 0; s0 < T; s0 += 64) {
    if (s0) __syncthreads();       // protect ks reuse
#pragma unroll
    for (int i = 0; i < 16; i++) {
      int e = tid + i * 256;
      int r = e >> 6, c = e & 63;
      ks[r][c] = kb[(size_t)(b * T + s0 + r) * D + h * HS + c];
    }
    __syncthreads();
#pragma unroll
    for (int i = 0; i < 2; i++) {
      int e = tid + i * 256;
      int r = e >> 6, c = e & 63;   // r: 0..7 row, c: 0..63 col within chunk
      float s = 0.0f;
#pragma unroll
      for (int d = 0; d < HS; d++) s += qs[r][d] * ks[c][d];
      sc[r][s0 + c] = s * 0.125f;   // HS^-0.5
    }
  }
  __syncthreads();
  // softmax: 32 threads per row
  int r  = tid >> 5;
  int i2 = tid & 31;
  float m = -1e30f;
#pragma unroll
  for (int j = 0; j < 32; j++) m = fmaxf(m, sc[r][i2 + j * 32]);
#pragma unroll
  for (int mk = 16; mk; mk >>= 1) m = fmaxf(m, __shfl_xor(m, mk));
  float sum = 0.0f;
#pragma unroll
  for (int j = 0; j < 32; j++) {
    float e = __expf(sc[r][i2 + j * 32] - m);
    sc[r][i2 + j * 32] = e;
    sum += e;
  }
#pragma unroll
  for (int mk = 16; mk; mk >>= 1) sum += __shfl_xor(sum, mk);
  float inv = 1.0f / sum;
  size_t base = (((size_t)(l * H + h) * B + b) * T + (t0 + r)) * T;
#pragma unroll
  for (int j = 0; j < 32; j++) wout[base + i2 + j * 32] = sc[r][i2 + j * 32] * inv;
}

// ---------------------------------------------------------------------------
// PV: o[b, t, h*64+e] = sum_s w[l,h,b,t,s] * v[b, s, h*64+e]
// Tiled GEMM per (b,h): M=T, N=64, K=T. Grid: (T/64, 1, B*H).
// ---------------------------------------------------------------------------
__global__ __launch_bounds__(256) void k_attn_pv(const float* __restrict__ wmap,
                                                 const float* __restrict__ vb,
                                                 float* __restrict__ o,
                                                 int l) {
  __shared__ float As[64][17];
  __shared__ float Bs[16][65];
  int bh = blockIdx.z;
  int b = bh >> 2, h = bh & 3;
  const float* A  = wmap + ((size_t)(l * H + h) * B + b) * T * T;  // [T][T]
  const float* Bm = vb + (size_t)b * T * D + h * HS;               // [T][64], ld D
  float* C        = o + (size_t)b * T * D + h * HS;
  int row0 = blockIdx.x * 64;
  int tid = threadIdx.x;
  int tx = tid & 15, ty = tid >> 4;
  float acc[4][4] = {};
  for (int k0 = 0; k0 < T; k0 += 16) {
#pragma unroll
    for (int i = 0; i < 4; i++) {
      int e = tid + i * 256;
      int r = e >> 4, c = e & 15;
      As[r][c] = A[(size_t)(row0 + r) * T + k0 + c];
    }
#pragma unroll
    for (int i = 0; i < 4; i++) {
      int e = tid + i * 256;
      int r = e >> 6, c = e & 63;
      Bs[r][c] = Bm[(size_t)(k0 + r) * D + c];
    }
    __syncthreads();
#pragma unroll
    for (int kk = 0; kk < 16; kk++) {
      float a[4], bb[4];
#pragma unroll
      for (int i = 0; i < 4; i++) a[i] = As[ty * 4 + i][kk];
#pragma unroll
      for (int j = 0; j < 4; j++) bb[j] = Bs[kk][tx * 4 + j];
#pragma unroll
      for (int i = 0; i < 4; i++)
#pragma unroll
        for (int j = 0; j < 4; j++) acc[i][j] += a[i] * bb[j];
    }
    __syncthreads();
  }
#pragma unroll
  for (int i = 0; i < 4; i++)
#pragma unroll
    for (int j = 0; j < 4; j++)
      C[(size_t)(row0 + ty * 4 + i) * D + tx * 4 + j] = acc[i][j];
}

// ---------------------------------------------------------------------------
// Pool stage 1: partial sums over 128-token chunks. Grid (B, 8).
// ---------------------------------------------------------------------------
__global__ __launch_bounds__(256) void k_pool1(const float* __restrict__ xn,
                                               float* __restrict__ part) {
  int b = blockIdx.x, cb = blockIdx.y, d = threadIdx.x;
  float s = 0.0f;
  int t0 = cb * 128;
  for (int t = 0; t < 128; t++) s += xn[(size_t)(b * T + t0 + t) * D + d];
  part[(size_t)(b * 8 + cb) * D + d] = s;
}

__global__ __launch_bounds__(256) void k_pool2(const float* __restrict__ part,
                                               float* __restrict__ pooled) {
  int b = blockIdx.x, d = threadIdx.x;
  float s = 0.0f;
#pragma unroll
  for (int cb = 0; cb < 8; cb++) s += part[(size_t)(b * 8 + cb) * D + d];
  pooled[(size_t)b * D + d] = s * (1.0f / T);
}

// ---------------------------------------------------------------------------
// Classifier head: logits = relu(pooled @ cW1 + cb1) @ cW2 + cb2. One block.
// ---------------------------------------------------------------------------
__global__ __launch_bounds__(256) void k_cls(const float* __restrict__ pooled,
                                             const float* __restrict__ cW1,
                                             const float* __restrict__ cb1,
                                             const float* __restrict__ cW2,
                                             const float* __restrict__ cb2,
                                             float* __restrict__ out) {
  __shared__ float pl[D];
  __shared__ float hid[CH];
  int tid = threadIdx.x;
  for (int b = 0; b < B; b++) {
    pl[tid] = pooled[(size_t)b * D + tid];
    __syncthreads();
    float s = cb1[tid];
    for (int d = 0; d < D; d++) s += pl[d] * cW1[(size_t)d * CH + tid];
    hid[tid] = fmaxf(s, 0.0f);
    __syncthreads();
    if (tid < NOUT) {
      float s2 = cb2[tid];
      for (int c = 0; c < CH; c++) s2 += hid[c] * cW2[(size_t)c * NOUT + tid];
      out[b * NOUT + tid] = s2;
    }
    __syncthreads();
  }
}

// ---------------------------------------------------------------------------
// Host launcher
// ---------------------------------------------------------------------------
extern "C" void kernel_launch(void* const* d_in, const int* in_sizes, int n_in,
                              void* d_out, int out_size, void* d_ws, size_t ws_size,
                              hipStream_t stream) {
  const int*   idx    = (const int*)  d_in[0];
  const float* tok    = (const float*)d_in[1];
  const float* pos    = (const float*)d_in[2];
  const float* Wq     = (const float*)d_in[3];
  const float* Wk     = (const float*)d_in[4];
  const float* Wv     = (const float*)d_in[5];
  const float* Wproj  = (const float*)d_in[6];
  const float* bproj  = (const float*)d_in[7];
  const float* ln1_g  = (const float*)d_in[8];
  const float* ln1_b  = (const float*)d_in[9];
  const float* ln2_g  = (const float*)d_in[10];
  const float* ln2_b  = (const float*)d_in[11];
  const float* W1     = (const float*)d_in[12];
  const float* b1     = (const float*)d_in[13];
  const float* W2     = (const float*)d_in[14];
  const float* b2     = (const float*)d_in[15];
  const float* lnf_g  = (const float*)d_in[16];
  const float* lnf_b  = (const float*)d_in[17];
  const float* cW1    = (const float*)d_in[18];
  const float* cb1    = (const float*)d_in[19];
  const float* cW2    = (const float*)d_in[20];
  const float* cb2    = (const float*)d_in[21];

  float* out  = (float*)d_out;
  float* attn = out + 16;                      // maps after the 16 logits

  float* ws = (float*)d_ws;
  float* x      = ws;                          // [8192][256]
  float* xn     = x  + (size_t)M_TOK * D;      // [8192][256]
  float* q      = xn + (size_t)M_TOK * D;      // [8192][256]
  float* k      = q  + (size_t)M_TOK * D;
  float* v      = k  + (size_t)M_TOK * D;
  float* o      = v  + (size_t)M_TOK * D;
  float* ffh    = q;                           // [8192][1024] aliases q..o (dead then)
  float* pooled = o  + (size_t)M_TOK * D;      // [8][256]
  float* part   = pooled + B * D;              // [8][8][256]
  float* wrm    = part + B * 8 * D;            // [L][3][256][256]

  k_embed<<<M_TOK / 4, 256, 0, stream>>>(idx, tok, pos, x);
  k_prep_qkv<<<L * 3 * D, 256, 0, stream>>>(Wq, Wk, Wv, wrm);

  for (int l = 0; l < L; l++) {
    k_ln<<<M_TOK / 4, 256, 0, stream>>>(x, ln1_g + l * D, ln1_b + l * D, xn);

    dim3 gq(M_TOK / 64, D / 64);
    k_gemm<0, 0, 0><<<gq, 256, 0, stream>>>(xn, D, wrm + (size_t)(l * 3 + 0) * D * D, D, nullptr, q, D, D);
    k_gemm<0, 0, 0><<<gq, 256, 0, stream>>>(xn, D, wrm + (size_t)(l * 3 + 1) * D * D, D, nullptr, k, D, D);
    k_gemm<0, 0, 0><<<gq, 256, 0, stream>>>(xn, D, wrm + (size_t)(l * 3 + 2) * D * D, D, nullptr, v, D, D);

    k_attn_qk<<<dim3(T / 8, H, B), 256, 0, stream>>>(q, k, attn, l);
    k_attn_pv<<<dim3(T / 64, 1, B * H), 256, 0, stream>>>(attn, v, o, l);

    k_gemm<1, 0, 1><<<dim3(M_TOK / 64, D / 64), 256, 0, stream>>>(
        o, D, Wproj + (size_t)l * D * D, D, bproj + l * D, x, D, D);

    k_ln<<<M_TOK / 4, 256, 0, stream>>>(x, ln2_g + l * D, ln2_b + l * D, xn);

    k_gemm<1, 1, 0><<<dim3(M_TOK / 64, FF / 64), 256, 0, stream>>>(
        xn, D, W1 + (size_t)l * D * FF, FF, b1 + l * FF, ffh, FF, D);

    k_gemm<1, 0, 1><<<dim3(M_TOK / 64, D / 64), 256, 0, stream>>>(
        ffh, FF, W2 + (size_t)l * FF * D, D, b2 + l * D, x, D, FF);
  }

  k_ln<<<M_TOK / 4, 256, 0, stream>>>(x, lnf_g, lnf_b, xn);
  k_pool1<<<dim3(B, 8), 256, 0, stream>>>(xn, part);
  k_pool2<<<B, 256, 0, stream>>>(part, pooled);
  k_cls<<<1, 256, 0, stream>>>(pooled, cW1, cb1, cW2, cb2, out);
}